// Round 5
// baseline (143.774 us; speedup 1.0000x reference)
//
#include <hip/hip_runtime.h>
#include <hip/hip_bf16.h>
#include <math.h>

#define N_CLS 16384
#define DDIM  128
#define LOG2E 1.4426950408889634f

#if __has_builtin(__builtin_amdgcn_exp2f)
#define EXP2(x) __builtin_amdgcn_exp2f(x)
#else
#define EXP2(x) exp2f(x)
#endif

typedef __attribute__((ext_vector_type(8))) short short8;   // 8 bf16 (4 VGPRs)
typedef __attribute__((ext_vector_type(16))) float f32x16;  // 32x32 MFMA accumulator

__device__ __forceinline__ unsigned short f2bf(float f) {
    __hip_bfloat16 h = __float2bfloat16(f);
    return *(unsigned short*)&h;
}

// ---------------------------------------------------------------------------
// 32x32x16 fragment layout (harness-verified r1/r2):
//   element (rr, k) of a 32-row tile, K=128 in 8 kc chunks:
//     lane = (k>>3 & 1)*32 + (rr&31), j = k&7
//     short offset = tile*4096 + kc*512 + lane*8 + j     (tile = 8 KB)
//
// prep (r2 coalesced version, verified): block = 32 pairs (64 x-rows).
// 16 consecutive threads read 512 B contiguous of one row; even-row threads
// also load partner row for anchor select + ap dot (4-step shfl reduce).
// No CSHIFT (|S|max ~70 -> exp2 args within +-102, f32-safe).
// ---------------------------------------------------------------------------
__global__ __launch_bounds__(256)
void prep_kernel(const float* __restrict__ x,
                 const int* __restrict__ aidx,
                 float* __restrict__ ap,
                 unsigned short* __restrict__ Afrag,
                 unsigned short* __restrict__ Bfrag,
                 float* __restrict__ out) {
    const int t = threadIdx.x;
    const int g = blockIdx.x;                  // 32 pairs per block (512 blocks)
    #pragma unroll
    for (int u = 0; u < 4; ++u) {
        const int l  = u * 256 + t;            // unit in [0,1024)
        const int r  = l >> 4;                 // slab row 0..63
        const int k0 = (l & 15) * 8;
        const float* src = x + (long)g * 8192 + (long)r * 128 + k0;
        float fa[8];
        *(float4*)&fa[0] = *(const float4*)(src);
        *(float4*)&fa[4] = *(const float4*)(src + 4);
        // frag dest: kc = (l&15)>>1, half = l&1, rr = r>>1
        const long dst = (long)g * 4096 +
                         ((l & 15) >> 1) * 512 + ((l & 1) * 32 + (r >> 1)) * 8;
        if (r & 1) {
            short8 B;
            #pragma unroll
            for (int j = 0; j < 8; ++j) B[j] = (short)f2bf(fa[j]);
            *(short8*)(Bfrag + dst) = B;
        } else {
            float fb[8];
            *(float4*)&fb[0] = *(const float4*)(src + 128);
            *(float4*)&fb[4] = *(const float4*)(src + 132);
            const int i = g * 32 + (r >> 1);
            const bool sel = (aidx[i] != 0);
            short8 A;
            float d = 0.0f;
            #pragma unroll
            for (int j = 0; j < 8; ++j) {
                const float av = sel ? fb[j] : fa[j];
                A[j] = (short)f2bf(av * LOG2E);
                d += fa[j] * fb[j];
            }
            *(short8*)(Afrag + dst) = A;
            d += __shfl_xor(d, 1, 64);
            d += __shfl_xor(d, 2, 64);
            d += __shfl_xor(d, 4, 64);
            d += __shfl_xor(d, 8, 64);
            if ((t & 15) == 0) ap[i] = d;
        }
    }
    if (t == 0 && g == 0) out[0] = 0.0f;
}

// ---------------------------------------------------------------------------
// fused v4: r2 LDS structure + restored acc A/B software pipeline.
// r2 diagnosis: MfmaUtil 37% == the 27.3 us MFMA floor spread over 77 us.
// Per tile the epilogue (32 exp2 + 32 add, ~400 VALU cyc) depended on its
// OWN tile's 8-deep MFMA chain -> serial phases, and 2 lockstepped
// waves/SIMD had nothing to fill the gaps. Now: compute tile t into slot X
// while epiloguing tile t-1 from slot Y (independent -> compiler interleaves;
// VALU hides under MFMA). Statically 2x-unrolled (no runtime acc indexing).
// Kept from r2 (verified): block = 256 rows x 2048-col octant (bid&7
// XCD-aligned), B tile double-buffered in LDS (issue-early/write-late),
// wave owns 2 row-tiles, one barrier/tile, diagonal zeroed via wave-uniform
// tile index. VGPR ~220 (2 waves/SIMD; grid-limited there anyway).
// Spill signature to watch: WRITE_SIZE >> 512 KB.
// ---------------------------------------------------------------------------
__global__ __launch_bounds__(256, 2)
void fused_kernel(const unsigned short* __restrict__ Afrag,
                  const unsigned short* __restrict__ Bfrag,
                  float* __restrict__ partial) {
    __shared__ __align__(16) unsigned short bs[2][4096];   // 2 x 8 KB
    const int tid  = threadIdx.x;
    const int lane = tid & 63;
    const int w    = tid >> 6;                 // wave 0..3
    const int l31  = lane & 31;
    const int hi   = lane >> 5;
    const int oct  = blockIdx.x & 7;           // XCD-aligned column octant
    const int rt   = blockIdx.x >> 3;          // 0..63 (256-row block)
    const int r0   = rt * 8 + w * 2;           // this wave's 32-row tiles
    const int r1   = r0 + 1;

    // hoist A: two 32-row tiles, all 8 kc (64 VGPRs)
    short8 af0[8], af1[8];
    {
        const unsigned short* a0 = Afrag + (long)r0 * 4096 + lane * 8;
        const unsigned short* a1 = Afrag + (long)r1 * 4096 + lane * 8;
        #pragma unroll
        for (int kc = 0; kc < 8; ++kc) {
            af0[kc] = *(const short8*)(a0 + kc * 512);
            af1[kc] = *(const short8*)(a1 + kc * 512);
        }
    }
    const unsigned short* bbase = Bfrag + (long)oct * (64L * 4096) + lane * 8;
    const int wchunk = w * 1024;               // this wave's 2 stage chunks

    // diagonal col-tiles (wave-uniform); sentinel must never equal a prev-tile
    // index (prev can be -1 in the first pipelined epi call)
    int ctd0 = r0 - oct * 64;
    int ctd1 = r1 - oct * 64;
    if (ctd0 < 0 || ctd0 >= 64) ctd0 = -1000;
    if (ctd1 < 0 || ctd1 >= 64) ctd1 = -1000;

    float rs0[16], rs1[16];
    #pragma unroll
    for (int q = 0; q < 16; ++q) { rs0[q] = 0.0f; rs1[q] = 0.0f; }

    const f32x16 zacc = {0.0f, 0.0f, 0.0f, 0.0f, 0.0f, 0.0f, 0.0f, 0.0f,
                         0.0f, 0.0f, 0.0f, 0.0f, 0.0f, 0.0f, 0.0f, 0.0f};
    f32x16 aA0, aA1, aB0, aB1;                 // two pipeline slots

    auto compute = [&](f32x16& c0, f32x16& c1, const unsigned short* bp) {
        #pragma unroll
        for (int kc = 0; kc < 8; ++kc) {
            short8 b = *(const short8*)(bp + kc * 512);
            c0 = __builtin_amdgcn_mfma_f32_32x32x16_bf16(
                     af0[kc], b, (kc == 0) ? zacc : c0, 0, 0, 0);
            c1 = __builtin_amdgcn_mfma_f32_32x32x16_bf16(
                     af1[kc], b, (kc == 0) ? zacc : c1, 0, 0, 0);
        }
    };
    auto epi = [&](f32x16& p0, f32x16& p1, int pt) {
        if (pt == ctd0) {
            #pragma unroll
            for (int q = 0; q < 16; ++q) {
                const float e = EXP2(p0[q]);
                const int row = (q & 3) + 8 * (q >> 2) + 4 * hi;  // C/D row map
                rs0[q] += (l31 == row) ? 0.0f : e;
            }
        } else {
            #pragma unroll
            for (int q = 0; q < 16; ++q) rs0[q] += EXP2(p0[q]);
        }
        if (pt == ctd1) {
            #pragma unroll
            for (int q = 0; q < 16; ++q) {
                const float e = EXP2(p1[q]);
                const int row = (q & 3) + 8 * (q >> 2) + 4 * hi;
                rs1[q] += (l31 == row) ? 0.0f : e;
            }
        } else {
            #pragma unroll
            for (int q = 0; q < 16; ++q) rs1[q] += EXP2(p1[q]);
        }
    };
    // one pipeline step: stage tile t+1 (issue-early), compute tile t into
    // (c0,c1), epilogue tile pt from (p0,p1), write staged data (late), barrier
    auto step = [&](int t, f32x16& c0, f32x16& c1,
                    f32x16& p0, f32x16& p1, int pt) {
        const int cur = t & 1;
        const long nt = (t < 63) ? (long)(t + 1) : 63L;   // 63 reloads itself
        short8 n0 = *(const short8*)(bbase + nt * 4096 + wchunk);
        short8 n1 = *(const short8*)(bbase + nt * 4096 + wchunk + 512);
        compute(c0, c1, &bs[cur][lane * 8]);
        if (pt >= 0) epi(p0, p1, pt);          // overlaps with MFMA chain above
        *(short8*)(&bs[cur ^ 1][wchunk + lane * 8]) = n0;
        *(short8*)(&bs[cur ^ 1][wchunk + 512 + lane * 8]) = n1;
        __syncthreads();
    };

    // prologue: stage tile 0 into bs[0]
    {
        short8 s0 = *(const short8*)(bbase + wchunk);
        short8 s1 = *(const short8*)(bbase + wchunk + 512);
        *(short8*)(&bs[0][wchunk + lane * 8]) = s0;
        *(short8*)(&bs[0][wchunk + 512 + lane * 8]) = s1;
    }
    __syncthreads();

    for (int t = 0; t < 64; t += 2) {
        step(t,     aA0, aA1, aB0, aB1, t - 1);   // compute even tile, epi odd
        step(t + 1, aB0, aB1, aA0, aA1, t);       // compute odd tile, epi even
    }
    epi(aB0, aB1, 63);                             // drain

    // cross-column reduce (l31 bits via xor 1..16), one store per output row
    #pragma unroll
    for (int q = 0; q < 16; ++q) {
        float v0 = rs0[q], v1 = rs1[q];
        v0 += __shfl_xor(v0, 1, 64);  v1 += __shfl_xor(v1, 1, 64);
        v0 += __shfl_xor(v0, 2, 64);  v1 += __shfl_xor(v1, 2, 64);
        v0 += __shfl_xor(v0, 4, 64);  v1 += __shfl_xor(v1, 4, 64);
        v0 += __shfl_xor(v0, 8, 64);  v1 += __shfl_xor(v1, 8, 64);
        v0 += __shfl_xor(v0, 16, 64); v1 += __shfl_xor(v1, 16, 64);
        if (l31 == 0) {
            const int row = (q & 3) + 8 * (q >> 2) + 4 * hi;
            partial[(long)oct * N_CLS + (long)r0 * 32 + row] = v0;
            partial[(long)oct * N_CLS + (long)r1 * 32 + row] = v1;
        }
    }
}

// ---------------------------------------------------------------------------
// finalize: per row s = sum of 8 octant partials (= sum_j exp(S_ij), j!=i);
// loss = log1p(s * exp(-ap)) via u = log(s) - ap; block-sum; atomicAdd.
// ---------------------------------------------------------------------------
__global__ __launch_bounds__(256)
void finalize_kernel(const float* __restrict__ partial,
                     const float* __restrict__ ap,
                     float* __restrict__ out) {
    __shared__ float red[256];
    const int t = threadIdx.x;
    const int row = blockIdx.x * 256 + t;
    float s = 0.0f;
    #pragma unroll
    for (int p = 0; p < 8; ++p) s += partial[(long)p * N_CLS + row];
    const float u = logf(s) - ap[row];
    const float loss = (u > 25.0f) ? u : log1pf(__expf(u));
    red[t] = loss;
    __syncthreads();
    for (int st = 128; st > 0; st >>= 1) {
        if (t < st) red[t] += red[t + st];
        __syncthreads();
    }
    if (t == 0) atomicAdd(out, red[0]);
}

extern "C" void kernel_launch(void* const* d_in, const int* in_sizes, int n_in,
                              void* d_out, int out_size, void* d_ws, size_t ws_size,
                              hipStream_t stream) {
    const float* x    = (const float*)d_in[0];
    const int*   aidx = (const int*)d_in[1];
    // d_in[2] (pos_idx) derivable; unused.

    char* ws = (char*)d_ws;
    float* ap             = (float*)(ws);                                   // 64 KB
    float* partial        = (float*)(ws + 131072);                          // 512 KB (8 slots)
    unsigned short* Afrag = (unsigned short*)(ws + 131072 + 1048576);       // 4 MB
    unsigned short* Bfrag = (unsigned short*)(ws + 131072 + 1048576 + 4194304); // 4 MB

    prep_kernel<<<N_CLS / 32, 256, 0, stream>>>(x, aidx, ap, Afrag, Bfrag, (float*)d_out);
    fused_kernel<<<512, 256, 0, stream>>>(Afrag, Bfrag, partial);
    finalize_kernel<<<64, 256, 0, stream>>>(partial, ap, (float*)d_out);
}